// Round 1
// baseline (996.526 us; speedup 1.0000x reference)
//
#include <hip/hip_runtime.h>
#include <hip/hip_bf16.h>
#include <math.h>

// Problem constants (fixed by setup_inputs)
#define B_  2
#define NH  4
#define HH  64
#define WW  64
#define KD  32
#define L_  4096            // HH*WW
#define BN_ 8               // B_*NH
#define SCALE 0.17677669529663687f   // 1/sqrt(32)

// ---------------------------------------------------------------------------
// Kernel A: qkv = x @ w_qkv  (M=8192, K=128, N=384), scatter into q/k/v
// layouts [b][head][l][32]. K is pre-scaled by 1/sqrt(32) (only used in QK).
// Tiled 64x64, Ktile=64, 256 threads, 4x4 microtile per thread.
// ---------------------------------------------------------------------------
__global__ __launch_bounds__(256) void qkv_gemm(const float* __restrict__ x,
                                                const float* __restrict__ w,
                                                float* __restrict__ q_ws,
                                                float* __restrict__ k_ws,
                                                float* __restrict__ v_ws) {
    __shared__ float As[64][68];   // padded: conflict-free staging + broadcast reads
    __shared__ float Bs[64][68];
    const int mt = blockIdx.x % 128;
    const int nt = blockIdx.x / 128;
    const int m0 = mt * 64, n0 = nt * 64;
    const int tid = threadIdx.x;
    const int ti = tid / 16, tj = tid % 16;
    float acc[4][4] = {};

    for (int k0 = 0; k0 < 128; k0 += 64) {
        #pragma unroll
        for (int i = 0; i < 16; i++) {          // 64x64 A tile
            int e = i * 256 + tid;
            int row = e >> 6, col = e & 63;
            As[row][col] = x[(m0 + row) * 128 + k0 + col];
        }
        #pragma unroll
        for (int i = 0; i < 16; i++) {          // 64x64 B tile
            int e = i * 256 + tid;
            int kk = e >> 6, col = e & 63;
            Bs[kk][col] = w[(k0 + kk) * 384 + n0 + col];
        }
        __syncthreads();
        #pragma unroll 8
        for (int kk = 0; kk < 64; kk++) {
            float av[4];
            #pragma unroll
            for (int r = 0; r < 4; r++) av[r] = As[ti * 4 + r][kk];
            const float4 b4 = *(const float4*)&Bs[kk][tj * 4];
            const float bv[4] = {b4.x, b4.y, b4.z, b4.w};
            #pragma unroll
            for (int r = 0; r < 4; r++)
                #pragma unroll
                for (int c = 0; c < 4; c++)
                    acc[r][c] = fmaf(av[r], bv[c], acc[r][c]);
        }
        __syncthreads();
    }

    // epilogue: n0 is a multiple of 64 so the tile is wholly inside q, k or v
    const int which = n0 >> 7;                 // 0=q, 1=k, 2=v
    float* dst = (which == 0) ? q_ws : (which == 1) ? k_ws : v_ws;
    const float mult = (which == 1) ? SCALE : 1.0f;
    const int nc = n0 & 127;
    #pragma unroll
    for (int r = 0; r < 4; r++) {
        const int m = m0 + ti * 4 + r;
        const int b = m >> 12, l = m & 4095;
        #pragma unroll
        for (int c = 0; c < 4; c++) {
            const int col = nc + tj * 4 + c;
            const int hd = col >> 5, d = col & 31;
            dst[((b * NH + hd) * L_ + l) * KD + d] = acc[r][c] * mult;
        }
    }
}

// ---------------------------------------------------------------------------
// Kernel B: absolute-indexed relative bias tables.
//   qw_abs[bn][w2][w1][h1] = dot(q[bn,h1,w1,:], emb_w[w2-w1+63,:])
//   qh_abs[bn][h2][w1][h1] = dot(q[bn,h1,w1,:], emb_h[h2-h1+63,:])
// One block per (bn, w1). Lane = h1 so table writes are coalesced.
// ---------------------------------------------------------------------------
__global__ __launch_bounds__(256) void bias_tables(const float* __restrict__ q_ws,
                                                   const float* __restrict__ emb_h,
                                                   const float* __restrict__ emb_w,
                                                   float* __restrict__ qw_abs,
                                                   float* __restrict__ qh_abs) {
    __shared__ float qs[64][33];     // +1 pad: per-lane h1 rows conflict-free
    __shared__ float ehs[127][33];
    __shared__ float ews[127][33];
    const int bn = blockIdx.x >> 6;
    const int w1 = blockIdx.x & 63;
    const int tid = threadIdx.x;

    #pragma unroll
    for (int i = 0; i < 8; i++) {            // q rows for all h1 at this w1
        int e = i * 256 + tid;               // 2048 = 64*32
        int h1 = e >> 5, d = e & 31;
        qs[h1][d] = q_ws[(bn * L_ + h1 * 64 + w1) * KD + d];
    }
    #pragma unroll
    for (int i = 0; i < 16; i++) {           // both embeddings, 127x32
        int e = i * 256 + tid;
        if (e < 127 * 32) {
            int r = e >> 5, d = e & 31;
            ehs[r][d] = emb_h[e];
            ews[r][d] = emb_w[e];
        }
    }
    __syncthreads();

    const int h1 = tid & 63;
    const int mg = tid >> 6;                 // 4 groups x 16 m2 values
    for (int mm = 0; mm < 16; mm++) {
        const int m2 = mg * 16 + mm;
        const float* qrow = &qs[h1][0];
        const float* erw  = &ews[m2 - w1 + 63][0];   // uniform row (broadcast)
        const float* erh  = &ehs[m2 - h1 + 63][0];   // per-lane row
        float sw = 0.f, sh = 0.f;
        #pragma unroll
        for (int d = 0; d < 32; d++) {
            sw = fmaf(qrow[d], erw[d], sw);
            sh = fmaf(qrow[d], erh[d], sh);
        }
        const int oidx = bn * (64 * L_) + m2 * L_ + w1 * 64 + h1;
        qw_abs[oidx] = sw;
        qh_abs[oidx] = sh;
    }
}

// ---------------------------------------------------------------------------
// Kernel C: flash attention. Block = (bn, w1): 4 waves x 64 lanes.
// lane = h1 (query), wave = key-split (16 rows of h2 each). Online softmax
// per lane; merge the 4 splits through LDS; write [B,H,W,C] output.
// ---------------------------------------------------------------------------
__global__ __launch_bounds__(256) void attn(const float* __restrict__ q_ws,
                                            const float* __restrict__ k_ws,
                                            const float* __restrict__ v_ws,
                                            const float* __restrict__ qw_abs,
                                            const float* __restrict__ qh_abs,
                                            float* __restrict__ out) {
    __shared__ float lds_acc[4][64][33];
    __shared__ float lds_m[4][64];
    __shared__ float lds_l[4][64];
    const int bn = blockIdx.x >> 6;
    const int w1 = blockIdx.x & 63;
    const int sp = threadIdx.x >> 6;     // key split 0..3
    const int lane = threadIdx.x & 63;   // h1

    float4 q4[8];
    const float4* qp = (const float4*)&q_ws[(bn * L_ + lane * 64 + w1) * KD];
    #pragma unroll
    for (int j = 0; j < 8; j++) q4[j] = qp[j];

    float m = -INFINITY, l = 0.f;
    float4 a4[8];
    #pragma unroll
    for (int j = 0; j < 8; j++) a4[j] = make_float4(0.f, 0.f, 0.f, 0.f);

    const float* qwb = qw_abs + bn * (64 * L_) + w1 * 64 + lane;
    const float* qhb = qh_abs + bn * (64 * L_) + w1 * 64 + lane;

    for (int h2 = sp * 16; h2 < sp * 16 + 16; h2++) {
        const float bh = qhb[h2 * L_];                        // coalesced
        const float4* krow = (const float4*)&k_ws[(bn * L_ + h2 * 64) * KD];
        const float4* vrow = (const float4*)&v_ws[(bn * L_ + h2 * 64) * KD];
        for (int w2 = 0; w2 < 64; w2++) {
            float s = bh + qwb[w2 * L_];                      // coalesced
            const float4* kp = krow + w2 * 8;                 // broadcast loads
            #pragma unroll
            for (int j = 0; j < 8; j++) {
                const float4 kv = kp[j];
                s = fmaf(q4[j].x, kv.x, s); s = fmaf(q4[j].y, kv.y, s);
                s = fmaf(q4[j].z, kv.z, s); s = fmaf(q4[j].w, kv.w, s);
            }
            if (s > m) {                                      // rare rescale
                const float alpha = __expf(m - s);
                m = s;
                l *= alpha;
                #pragma unroll
                for (int j = 0; j < 8; j++) {
                    a4[j].x *= alpha; a4[j].y *= alpha;
                    a4[j].z *= alpha; a4[j].w *= alpha;
                }
            }
            const float p = __expf(s - m);
            l += p;
            const float4* vp = vrow + w2 * 8;                 // broadcast loads
            #pragma unroll
            for (int j = 0; j < 8; j++) {
                const float4 vv = vp[j];
                a4[j].x = fmaf(p, vv.x, a4[j].x); a4[j].y = fmaf(p, vv.y, a4[j].y);
                a4[j].z = fmaf(p, vv.z, a4[j].z); a4[j].w = fmaf(p, vv.w, a4[j].w);
            }
        }
    }

    // dump per-split partials
    #pragma unroll
    for (int j = 0; j < 8; j++) {
        lds_acc[sp][lane][4 * j + 0] = a4[j].x;
        lds_acc[sp][lane][4 * j + 1] = a4[j].y;
        lds_acc[sp][lane][4 * j + 2] = a4[j].z;
        lds_acc[sp][lane][4 * j + 3] = a4[j].w;
    }
    lds_m[sp][lane] = m;
    lds_l[sp][lane] = l;
    __syncthreads();

    // merge: thread = (h1, quarter of d-range)
    const int h1 = threadIdx.x >> 2;
    const int qd = threadIdx.x & 3;
    const float m0 = lds_m[0][h1], m1 = lds_m[1][h1];
    const float m2v = lds_m[2][h1], m3 = lds_m[3][h1];
    const float M = fmaxf(fmaxf(m0, m1), fmaxf(m2v, m3));
    const float e0 = __expf(m0 - M), e1 = __expf(m1 - M);
    const float e2 = __expf(m2v - M), e3 = __expf(m3 - M);
    const float denom = e0 * lds_l[0][h1] + e1 * lds_l[1][h1]
                      + e2 * lds_l[2][h1] + e3 * lds_l[3][h1];
    const float inv = 1.0f / denom;
    const int b = bn >> 2, n = bn & 3;
    float* op = &out[((b * HH + h1) * WW + w1) * 128 + n * KD + qd * 8];
    #pragma unroll
    for (int j = 0; j < 8; j++) {
        const int d = qd * 8 + j;
        const float o = e0 * lds_acc[0][h1][d] + e1 * lds_acc[1][h1][d]
                      + e2 * lds_acc[2][h1][d] + e3 * lds_acc[3][h1][d];
        op[j] = o * inv;
    }
}

// ---------------------------------------------------------------------------
extern "C" void kernel_launch(void* const* d_in, const int* in_sizes, int n_in,
                              void* d_out, int out_size, void* d_ws, size_t ws_size,
                              hipStream_t stream) {
    const float* x     = (const float*)d_in[0];   // [2,64,64,128]
    const float* w_qkv = (const float*)d_in[1];   // [128,384]
    const float* emb_h = (const float*)d_in[2];   // [127,32]
    const float* emb_w = (const float*)d_in[3];   // [127,32]
    float* out = (float*)d_out;

    // workspace layout (floats): q,k,v 1M each; qw_abs,qh_abs 2M each = 28 MB
    float* q_ws   = (float*)d_ws;
    float* k_ws   = q_ws + (size_t)BN_ * L_ * KD;
    float* v_ws   = k_ws + (size_t)BN_ * L_ * KD;
    float* qw_abs = v_ws + (size_t)BN_ * L_ * KD;
    float* qh_abs = qw_abs + (size_t)BN_ * 64 * L_;

    qkv_gemm<<<768, 256, 0, stream>>>(x, w_qkv, q_ws, k_ws, v_ws);
    bias_tables<<<512, 256, 0, stream>>>(q_ws, emb_h, emb_w, qw_abs, qh_abs);
    attn<<<512, 256, 0, stream>>>(q_ws, k_ws, v_ws, qw_abs, qh_abs, out);
}